// Round 4
// baseline (1616.137 us; speedup 1.0000x reference)
//
#include <hip/hip_runtime.h>

#define NLAT 721
#define NLON 1440
#define NB 4
#define ND 5
#define NROWS (NLAT*ND)          // 3605
#define PLANE (NLAT*NLON)        // 1,038,240
#define HVOL (NB*PLANE)          // 4,152,960
#define DTSTEP 0.01f
#define LDSCAP 2048              // max taps staged in LDS per lat (real max ~1500)
#define TAPCAP 262144

// ---------------------------------------------------------------------------
// Kernel A: per (lat,d) row, find the wrapped-interval support [jlo, jhi]
// ---------------------------------------------------------------------------
__global__ __launch_bounds__(64) void support_kernel(
    const float* __restrict__ Kgc, const float* __restrict__ Kgs,
    const float* __restrict__ Kdc, const float* __restrict__ Kds,
    int* __restrict__ jlo_a, int* __restrict__ cnt_a)
{
  int row = blockIdx.x;
  int lane = threadIdx.x;
  const float* a = Kgc + (size_t)row * NLON;
  const float* b = Kgs + (size_t)row * NLON;
  const float* c = Kdc + (size_t)row * NLON;
  const float* d = Kds + (size_t)row * NLON;
  int jmin = 1 << 30, jmax = -(1 << 30);
  for (int m = lane; m < NLON; m += 64) {
    float s = fabsf(a[m]) + fabsf(b[m]) + fabsf(c[m]) + fabsf(d[m]);
    if (s != 0.0f) {
      int j = (m >= NLON / 2) ? (m - NLON) : m;
      jmin = min(jmin, j);
      jmax = max(jmax, j);
    }
  }
  for (int s = 32; s > 0; s >>= 1) {
    jmin = min(jmin, __shfl_down(jmin, s));
    jmax = max(jmax, __shfl_down(jmax, s));
  }
  if (lane == 0) {
    if (jmax < jmin) { jlo_a[row] = 0; cnt_a[row] = 0; }
    else             { jlo_a[row] = jmin; cnt_a[row] = jmax - jmin + 1; }
  }
}

// ---------------------------------------------------------------------------
// Kernel B: prefix sum over row counts; per-row meta int4(iq*NLON, jlo, rcnt,
// poolofs); per-lat pool [offset,total].
// ---------------------------------------------------------------------------
__global__ __launch_bounds__(256) void scan_kernel(
    const int* __restrict__ cnt_a, const int* __restrict__ jlo_a,
    int* __restrict__ off_a,
    int* __restrict__ latoff, int* __restrict__ latcnt,
    int4* __restrict__ rowmeta, int tap_cap)
{
  __shared__ int buf[256];
  __shared__ int carry;
  int tid = threadIdx.x;
  if (tid == 0) carry = 0;
  __syncthreads();
  for (int base = 0; base < NROWS; base += 256) {
    int i = base + tid;
    int v = (i < NROWS) ? cnt_a[i] : 0;
    buf[tid] = v;
    __syncthreads();
    for (int s = 1; s < 256; s <<= 1) {
      int t = (tid >= s) ? buf[tid - s] : 0;
      __syncthreads();
      buf[tid] += t;
      __syncthreads();
    }
    if (i < NROWS) off_a[i] = carry + buf[tid] - v;   // exclusive
    __syncthreads();
    if (tid == 255) carry += buf[255];
    __syncthreads();
  }
  __syncthreads();
  for (int r = tid; r < NROWS; r += 256) {
    int off = off_a[r];
    int c   = cnt_a[r];
    if (off >= tap_cap)          c = 0;
    else if (off + c > tap_cap)  c = tap_cap - off;
    int l = r / ND, d = r - ND * l;
    int iq = min(max(l + d - 2, 0), NLAT - 1);
    rowmeta[r] = make_int4(iq * NLON, jlo_a[r], c, off);
  }
  for (int l = tid; l < NLAT; l += 256) {
    int s0 = min(off_a[5 * l], tap_cap);
    int e  = min(off_a[5 * l + 4] + cnt_a[5 * l + 4], tap_cap);
    latoff[l] = s0;
    latcnt[l] = max(0, e - s0);
  }
}

// ---------------------------------------------------------------------------
// Kernel C: fill packed weight pool (weights only; meta is per-row).
// ---------------------------------------------------------------------------
__global__ __launch_bounds__(64) void fill_kernel(
    const float* __restrict__ Kgc, const float* __restrict__ Kgs,
    const float* __restrict__ Kdc, const float* __restrict__ Kds,
    const int* __restrict__ jlo_a, const int* __restrict__ cnt_a,
    const int* __restrict__ off_a,
    float4* __restrict__ tapw, int tap_cap)
{
  int row = blockIdx.x;
  int jlo = jlo_a[row], cnt = cnt_a[row], off = off_a[row];
  for (int t = threadIdx.x; t < cnt; t += 64) {
    int p = off + t;
    if (p >= tap_cap) break;
    int j = jlo + t;
    int m = j + ((j < 0) ? NLON : 0);
    size_t idx = (size_t)row * NLON + m;
    tapw[p] = make_float4(Kgc[idx], Kgs[idx], Kdc[idx], Kds[idx]);
  }
}

// ---------------------------------------------------------------------------
// Unified stage kernel, per-thread column.  Grid (6, NLAT*NB), block 256.
// blockIdx.y -> (lat, batch) with heavy (polar) lats first, all batches
// adjacent so polar blocks dispatch earliest.
// mode 0: O = S0 + cdt*k        (stages 1-3)
// mode 1: O = (X1+2*X2+X3-S0)/3 + (DT/6)*k4   (final; Xh/Xuv is X3)
// ---------------------------------------------------------------------------
__global__ __launch_bounds__(256) void stage_kernel(
    const float* __restrict__ Xh,  const float* __restrict__ Xuv,
    const float* __restrict__ S0h, const float* __restrict__ S0uv,
    const float* __restrict__ X1h, const float* __restrict__ X1uv,
    const float* __restrict__ X2h, const float* __restrict__ X2uv,
    const float* __restrict__ fcor,
    const int* __restrict__ latoff, const int* __restrict__ latcnt,
    const int4* __restrict__ rowmeta, const float4* __restrict__ tapw,
    float* __restrict__ Oh, float* __restrict__ Ouv,
    float cdt, int mode)
{
  __shared__ float4 sw[LDSCAP];

  int y  = blockIdx.y;
  int ly = y >> 2;                 // NB == 4
  int b  = y & 3;
  int l  = (ly & 1) ? (NLAT - 1 - (ly >> 1)) : (ly >> 1);   // heavy-first
  int tid = threadIdx.x;
  int n = blockIdx.x * 256 + tid;
  bool act = n < NLON;

  int p0  = latoff[l];
  int cnt = latcnt[l];
  bool uselds = (cnt <= LDSCAP);

  if (uselds) {
    for (int t = tid; t < cnt; t += 256) sw[t] = tapw[p0 + t];
  }
  __syncthreads();

  const float* __restrict__ xh  = Xh  + (size_t)b * PLANE;
  const float* __restrict__ xuv = Xuv + (size_t)b * PLANE * 2;

  float ah = 0.f, au = 0.f, av = 0.f;
  if (act) {
    for (int r = 0; r < ND; ++r) {
      int4 rm = rowmeta[l * ND + r];
      int rcnt = rm.z;
      if (!rcnt) continue;
      int nn = n + rm.y;
      nn += (nn < 0)     ? NLON : 0;
      nn -= (nn >= NLON) ? NLON : 0;
      const float* __restrict__ xrh  = xh  + rm.x;
      const float* __restrict__ xruv = xuv + 2 * (size_t)rm.x;
      if (uselds) {
        int ofs = rm.w - p0;
        #pragma unroll 4
        for (int t = 0; t < rcnt; ++t) {
          float4 w = sw[ofs + t];
          float  hh = xrh[nn];
          float2 uv = *(const float2*)(xruv + 2 * nn);
          ah = fmaf(w.z, uv.x, ah); ah = fmaf(w.w, uv.y, ah);
          au = fmaf(w.x, hh, au);
          av = fmaf(w.y, hh, av);
          nn++; nn = (nn == NLON) ? 0 : nn;
        }
      } else {                      // safety fallback (unused in practice)
        #pragma unroll 4
        for (int t = 0; t < rcnt; ++t) {
          float4 w = tapw[rm.w + t];
          float  hh = xrh[nn];
          float2 uv = *(const float2*)(xruv + 2 * nn);
          ah = fmaf(w.z, uv.x, ah); ah = fmaf(w.w, uv.y, ah);
          au = fmaf(w.x, hh, au);
          av = fmaf(w.y, hh, av);
          nn++; nn = (nn == NLON) ? 0 : nn;
        }
      }
    }
  }

  if (act) {
    size_t ih  = (size_t)b * PLANE + (size_t)l * NLON + n;
    size_t iuv = 2 * ih;
    float f = fcor[l];
    float2 xc = *(const float2*)(Xuv + iuv);   // current state's uv at point
    float kh = -ah;                            // dh = -H0 * corr
    float ku = fmaf(-f, xc.y, -au);            // du - f*v
    float kv = fmaf( f, xc.x, -av);            // dv + f*u
    if (mode == 0) {
      Oh[ih] = fmaf(cdt, kh, S0h[ih]);
      float2 s0 = *(const float2*)(S0uv + iuv);
      float2 o;
      o.x = fmaf(cdt, ku, s0.x);
      o.y = fmaf(cdt, kv, s0.y);
      *(float2*)(Ouv + iuv) = o;
    } else {
      const float DT6 = DTSTEP / 6.0f;
      const float TH  = 1.0f / 3.0f;
      // out = S0 + dt/6*(k1+2k2+2k3+k4) = (X1 + 2*X2 + X3 - S0)/3 + dt/6*k4
      float oh = TH * (X1h[ih] + 2.0f * X2h[ih] + Xh[ih] - S0h[ih]) + DT6 * kh;
      Oh[ih] = oh;
      float2 s0 = *(const float2*)(S0uv + iuv);
      float2 x1 = *(const float2*)(X1uv + iuv);
      float2 x2 = *(const float2*)(X2uv + iuv);
      float2 o;
      o.x = TH * (x1.x + 2.0f * x2.x + xc.x - s0.x) + DT6 * ku;
      o.y = TH * (x1.y + 2.0f * x2.y + xc.y - s0.y) + DT6 * kv;
      *(float2*)(Ouv + iuv) = o;
    }
  }
}

// ---------------------------------------------------------------------------
extern "C" void kernel_launch(void* const* d_in, const int* in_sizes, int n_in,
                              void* d_out, int out_size, void* d_ws, size_t ws_size,
                              hipStream_t stream)
{
  const float* h0   = (const float*)d_in[0];
  const float* uv0  = (const float*)d_in[1];
  const float* Kgc  = (const float*)d_in[2];
  const float* Kgs  = (const float*)d_in[3];
  const float* Kdc  = (const float*)d_in[4];
  const float* Kds  = (const float*)d_in[5];
  const float* fcor = (const float*)d_in[6];

  char* ws = (char*)d_ws;
  size_t pos = 0;
  auto carve = [&](size_t bytes) -> void* {
    void* p = ws + pos;
    pos += (bytes + 255) & ~(size_t)255;
    return p;
  };

  int*   jlo_a   = (int*)carve(sizeof(int) * NROWS);
  int*   cnt_a   = (int*)carve(sizeof(int) * NROWS);
  int*   off_a   = (int*)carve(sizeof(int) * NROWS);
  int*   latoff  = (int*)carve(sizeof(int) * NLAT);
  int*   latcnt  = (int*)carve(sizeof(int) * NLAT);
  int4*  rowmeta = (int4*)carve(sizeof(int4) * NROWS);
  float* X1      = (float*)carve(sizeof(float) * 3 * (size_t)HVOL);
  float* X2      = (float*)carve(sizeof(float) * 3 * (size_t)HVOL);
  float* X3      = (float*)carve(sizeof(float) * 3 * (size_t)HVOL);
  float4* tapw   = (float4*)carve(sizeof(float4) * (size_t)TAPCAP);

  float* X1h = X1;  float* X1uv = X1 + HVOL;
  float* X2h = X2;  float* X2uv = X2 + HVOL;
  float* X3h = X3;  float* X3uv = X3 + HVOL;
  float* out_h  = (float*)d_out;          // [NB,1,NLAT,NLON]
  float* out_uv = (float*)d_out + HVOL;   // [NB,1,NLAT,NLON,2]

  support_kernel<<<NROWS, 64, 0, stream>>>(Kgc, Kgs, Kdc, Kds, jlo_a, cnt_a);
  scan_kernel<<<1, 256, 0, stream>>>(cnt_a, jlo_a, off_a, latoff, latcnt,
                                     rowmeta, TAPCAP);
  fill_kernel<<<NROWS, 64, 0, stream>>>(Kgc, Kgs, Kdc, Kds, jlo_a, cnt_a, off_a,
                                        tapw, TAPCAP);

  dim3 gs(6, NLAT * NB);

  // stage 1: k1 from S0; X1 = S0 + dt/2 k1
  stage_kernel<<<gs, 256, 0, stream>>>(h0, uv0, h0, uv0, h0, uv0, h0, uv0, fcor,
                                       latoff, latcnt, rowmeta, tapw,
                                       X1h, X1uv, 0.5f * DTSTEP, 0);
  // stage 2: k2 from X1; X2 = S0 + dt/2 k2
  stage_kernel<<<gs, 256, 0, stream>>>(X1h, X1uv, h0, uv0, h0, uv0, h0, uv0, fcor,
                                       latoff, latcnt, rowmeta, tapw,
                                       X2h, X2uv, 0.5f * DTSTEP, 0);
  // stage 3: k3 from X2; X3 = S0 + dt k3
  stage_kernel<<<gs, 256, 0, stream>>>(X2h, X2uv, h0, uv0, h0, uv0, h0, uv0, fcor,
                                       latoff, latcnt, rowmeta, tapw,
                                       X3h, X3uv, DTSTEP, 0);
  // stage 4: k4 from X3; out = (X1 + 2 X2 + X3 - S0)/3 + dt/6 k4
  stage_kernel<<<gs, 256, 0, stream>>>(X3h, X3uv, h0, uv0, X1h, X1uv, X2h, X2uv, fcor,
                                       latoff, latcnt, rowmeta, tapw,
                                       out_h, out_uv, 0.0f, 1);
}

// Round 5
// 1168.383 us; speedup vs baseline: 1.3832x; 1.3832x over previous
//
#include <hip/hip_runtime.h>

#define NLAT 721
#define NLON 1440
#define NB 4
#define ND 5
#define NROWS (NLAT*ND)          // 3605
#define PLANE (NLAT*NLON)        // 1,038,240
#define HVOL (NB*PLANE)          // 4,152,960
#define DTSTEP 0.01f
#define LDSCAP 512               // weights staged per shot (8 KB LDS)
#define TAPCAP 262144

// ---------------------------------------------------------------------------
// Kernel A: per (lat,d) row, find the wrapped-interval support [jlo, jhi]
// ---------------------------------------------------------------------------
__global__ __launch_bounds__(64) void support_kernel(
    const float* __restrict__ Kgc, const float* __restrict__ Kgs,
    const float* __restrict__ Kdc, const float* __restrict__ Kds,
    int* __restrict__ jlo_a, int* __restrict__ cnt_a)
{
  int row = blockIdx.x;
  int lane = threadIdx.x;
  const float* a = Kgc + (size_t)row * NLON;
  const float* b = Kgs + (size_t)row * NLON;
  const float* c = Kdc + (size_t)row * NLON;
  const float* d = Kds + (size_t)row * NLON;
  int jmin = 1 << 30, jmax = -(1 << 30);
  for (int m = lane; m < NLON; m += 64) {
    float s = fabsf(a[m]) + fabsf(b[m]) + fabsf(c[m]) + fabsf(d[m]);
    if (s != 0.0f) {
      int j = (m >= NLON / 2) ? (m - NLON) : m;
      jmin = min(jmin, j);
      jmax = max(jmax, j);
    }
  }
  for (int s = 32; s > 0; s >>= 1) {
    jmin = min(jmin, __shfl_down(jmin, s));
    jmax = max(jmax, __shfl_down(jmax, s));
  }
  if (lane == 0) {
    if (jmax < jmin) { jlo_a[row] = 0; cnt_a[row] = 0; }
    else             { jlo_a[row] = jmin; cnt_a[row] = jmax - jmin + 1; }
  }
}

// ---------------------------------------------------------------------------
// Kernel B: prefix sum over row counts; per-row meta int4(iq*NLON, jlo, rcnt,
// poolofs); per-lat pool [offset,total].
// ---------------------------------------------------------------------------
__global__ __launch_bounds__(256) void scan_kernel(
    const int* __restrict__ cnt_a, const int* __restrict__ jlo_a,
    int* __restrict__ off_a,
    int* __restrict__ latoff, int* __restrict__ latcnt,
    int4* __restrict__ rowmeta, int tap_cap)
{
  __shared__ int buf[256];
  __shared__ int carry;
  int tid = threadIdx.x;
  if (tid == 0) carry = 0;
  __syncthreads();
  for (int base = 0; base < NROWS; base += 256) {
    int i = base + tid;
    int v = (i < NROWS) ? cnt_a[i] : 0;
    buf[tid] = v;
    __syncthreads();
    for (int s = 1; s < 256; s <<= 1) {
      int t = (tid >= s) ? buf[tid - s] : 0;
      __syncthreads();
      buf[tid] += t;
      __syncthreads();
    }
    if (i < NROWS) off_a[i] = carry + buf[tid] - v;   // exclusive
    __syncthreads();
    if (tid == 255) carry += buf[255];
    __syncthreads();
  }
  __syncthreads();
  for (int r = tid; r < NROWS; r += 256) {
    int off = off_a[r];
    int c   = cnt_a[r];
    if (off >= tap_cap)          c = 0;
    else if (off + c > tap_cap)  c = tap_cap - off;
    int l = r / ND, d = r - ND * l;
    int iq = min(max(l + d - 2, 0), NLAT - 1);
    rowmeta[r] = make_int4(iq * NLON, jlo_a[r], c, off);
  }
  for (int l = tid; l < NLAT; l += 256) {
    int s0 = min(off_a[5 * l], tap_cap);
    int e  = min(off_a[5 * l + 4] + cnt_a[5 * l + 4], tap_cap);
    latoff[l] = s0;
    latcnt[l] = max(0, e - s0);
  }
}

// ---------------------------------------------------------------------------
// Kernel C: fill packed weight pool (weights only; meta is per-row).
// ---------------------------------------------------------------------------
__global__ __launch_bounds__(64) void fill_kernel(
    const float* __restrict__ Kgc, const float* __restrict__ Kgs,
    const float* __restrict__ Kdc, const float* __restrict__ Kds,
    const int* __restrict__ jlo_a, const int* __restrict__ cnt_a,
    const int* __restrict__ off_a,
    float4* __restrict__ tapw, int tap_cap)
{
  int row = blockIdx.x;
  int jlo = jlo_a[row], cnt = cnt_a[row], off = off_a[row];
  for (int t = threadIdx.x; t < cnt; t += 64) {
    int p = off + t;
    if (p >= tap_cap) break;
    int j = jlo + t;
    int m = j + ((j < 0) ? NLON : 0);
    size_t idx = (size_t)row * NLON + m;
    tapw[p] = make_float4(Kgc[idx], Kgs[idx], Kdc[idx], Kds[idx]);
  }
}

// ---------------------------------------------------------------------------
// Unified stage kernel, per-thread column.  Grid (6, NLAT*NB), block 256.
// Small lats (cnt<=LDSCAP): whole lat's weights staged once.
// Big lats: per-row chunked staging (<=LDSCAP at a time, uniform syncs).
// mode 0: O = S0 + cdt*k        (stages 1-3)
// mode 1: O = (X1+2*X2+X3-S0)/3 + (DT/6)*k4   (final; Xh/Xuv is X3)
// ---------------------------------------------------------------------------
__global__ __launch_bounds__(256) void stage_kernel(
    const float* __restrict__ Xh,  const float* __restrict__ Xuv,
    const float* __restrict__ S0h, const float* __restrict__ S0uv,
    const float* __restrict__ X1h, const float* __restrict__ X1uv,
    const float* __restrict__ X2h, const float* __restrict__ X2uv,
    const float* __restrict__ fcor,
    const int* __restrict__ latoff, const int* __restrict__ latcnt,
    const int4* __restrict__ rowmeta, const float4* __restrict__ tapw,
    float* __restrict__ Oh, float* __restrict__ Ouv,
    float cdt, int mode)
{
  __shared__ float4 sw[LDSCAP];

  int y  = blockIdx.y;
  int ly = y >> 2;                 // NB == 4
  int b  = y & 3;
  int l  = (ly & 1) ? (NLAT - 1 - (ly >> 1)) : (ly >> 1);   // heavy-first
  int tid = threadIdx.x;
  int n = blockIdx.x * 256 + tid;
  bool act = n < NLON;

  int p0  = latoff[l];
  int cnt = latcnt[l];

  const float* __restrict__ xh  = Xh  + (size_t)b * PLANE;
  const float* __restrict__ xuv = Xuv + (size_t)b * PLANE * 2;

  float ah = 0.f, au = 0.f, av = 0.f;

  if (cnt <= LDSCAP) {
    // ---- small lat: stage whole pool once ----
    for (int t = tid; t < cnt; t += 256) sw[t] = tapw[p0 + t];
    __syncthreads();
    if (act) {
      for (int r = 0; r < ND; ++r) {
        int4 rm = rowmeta[l * ND + r];
        int rcnt = rm.z;
        if (!rcnt) continue;
        int nn = n + rm.y;
        nn += (nn < 0)     ? NLON : 0;
        nn -= (nn >= NLON) ? NLON : 0;
        const float* __restrict__ xrh  = xh  + rm.x;
        const float* __restrict__ xruv = xuv + 2 * (size_t)rm.x;
        int ofs = rm.w - p0;
        #pragma unroll 4
        for (int t = 0; t < rcnt; ++t) {
          float4 w = sw[ofs + t];
          float  hh = xrh[nn];
          float2 uv = *(const float2*)(xruv + 2 * nn);
          ah = fmaf(w.z, uv.x, ah); ah = fmaf(w.w, uv.y, ah);
          au = fmaf(w.x, hh, au);
          av = fmaf(w.y, hh, av);
          nn++; nn = (nn == NLON) ? 0 : nn;
        }
      }
    }
  } else {
    // ---- big (polar) lat: per-row chunked staging; syncs are uniform ----
    for (int r = 0; r < ND; ++r) {
      int4 rm = rowmeta[l * ND + r];     // wave-uniform (scalar loads)
      int rcnt = rm.z;
      if (!rcnt) continue;
      const float* __restrict__ xrh  = xh  + rm.x;
      const float* __restrict__ xruv = xuv + 2 * (size_t)rm.x;
      for (int c = 0; c < rcnt; c += LDSCAP) {
        int ccnt = min(LDSCAP, rcnt - c);
        __syncthreads();
        for (int t = tid; t < ccnt; t += 256) sw[t] = tapw[rm.w + c + t];
        __syncthreads();
        if (act) {
          int nn = n + rm.y + c;         // in [-720, ~3600): wrap into range
          nn += (nn < 0)            ? NLON : 0;
          nn -= (nn >= 2 * NLON)    ? NLON : 0;
          nn -= (nn >= NLON)        ? NLON : 0;
          #pragma unroll 4
          for (int t = 0; t < ccnt; ++t) {
            float4 w = sw[t];
            float  hh = xrh[nn];
            float2 uv = *(const float2*)(xruv + 2 * nn);
            ah = fmaf(w.z, uv.x, ah); ah = fmaf(w.w, uv.y, ah);
            au = fmaf(w.x, hh, au);
            av = fmaf(w.y, hh, av);
            nn++; nn = (nn == NLON) ? 0 : nn;
          }
        }
      }
    }
  }

  if (act) {
    size_t ih  = (size_t)b * PLANE + (size_t)l * NLON + n;
    size_t iuv = 2 * ih;
    float f = fcor[l];
    float2 xc = *(const float2*)(Xuv + iuv);   // current state's uv at point
    float kh = -ah;                            // dh = -H0 * corr
    float ku = fmaf(-f, xc.y, -au);            // du - f*v
    float kv = fmaf( f, xc.x, -av);            // dv + f*u
    if (mode == 0) {
      Oh[ih] = fmaf(cdt, kh, S0h[ih]);
      float2 s0 = *(const float2*)(S0uv + iuv);
      float2 o;
      o.x = fmaf(cdt, ku, s0.x);
      o.y = fmaf(cdt, kv, s0.y);
      *(float2*)(Ouv + iuv) = o;
    } else {
      const float DT6 = DTSTEP / 6.0f;
      const float TH  = 1.0f / 3.0f;
      // out = S0 + dt/6*(k1+2k2+2k3+k4) = (X1 + 2*X2 + X3 - S0)/3 + dt/6*k4
      float oh = TH * (X1h[ih] + 2.0f * X2h[ih] + Xh[ih] - S0h[ih]) + DT6 * kh;
      Oh[ih] = oh;
      float2 s0 = *(const float2*)(S0uv + iuv);
      float2 x1 = *(const float2*)(X1uv + iuv);
      float2 x2 = *(const float2*)(X2uv + iuv);
      float2 o;
      o.x = TH * (x1.x + 2.0f * x2.x + xc.x - s0.x) + DT6 * ku;
      o.y = TH * (x1.y + 2.0f * x2.y + xc.y - s0.y) + DT6 * kv;
      *(float2*)(Ouv + iuv) = o;
    }
  }
}

// ---------------------------------------------------------------------------
extern "C" void kernel_launch(void* const* d_in, const int* in_sizes, int n_in,
                              void* d_out, int out_size, void* d_ws, size_t ws_size,
                              hipStream_t stream)
{
  const float* h0   = (const float*)d_in[0];
  const float* uv0  = (const float*)d_in[1];
  const float* Kgc  = (const float*)d_in[2];
  const float* Kgs  = (const float*)d_in[3];
  const float* Kdc  = (const float*)d_in[4];
  const float* Kds  = (const float*)d_in[5];
  const float* fcor = (const float*)d_in[6];

  char* ws = (char*)d_ws;
  size_t pos = 0;
  auto carve = [&](size_t bytes) -> void* {
    void* p = ws + pos;
    pos += (bytes + 255) & ~(size_t)255;
    return p;
  };

  int*   jlo_a   = (int*)carve(sizeof(int) * NROWS);
  int*   cnt_a   = (int*)carve(sizeof(int) * NROWS);
  int*   off_a   = (int*)carve(sizeof(int) * NROWS);
  int*   latoff  = (int*)carve(sizeof(int) * NLAT);
  int*   latcnt  = (int*)carve(sizeof(int) * NLAT);
  int4*  rowmeta = (int4*)carve(sizeof(int4) * NROWS);
  float* X1      = (float*)carve(sizeof(float) * 3 * (size_t)HVOL);
  float* X2      = (float*)carve(sizeof(float) * 3 * (size_t)HVOL);
  float* X3      = (float*)carve(sizeof(float) * 3 * (size_t)HVOL);
  float4* tapw   = (float4*)carve(sizeof(float4) * (size_t)TAPCAP);

  float* X1h = X1;  float* X1uv = X1 + HVOL;
  float* X2h = X2;  float* X2uv = X2 + HVOL;
  float* X3h = X3;  float* X3uv = X3 + HVOL;
  float* out_h  = (float*)d_out;          // [NB,1,NLAT,NLON]
  float* out_uv = (float*)d_out + HVOL;   // [NB,1,NLAT,NLON,2]

  support_kernel<<<NROWS, 64, 0, stream>>>(Kgc, Kgs, Kdc, Kds, jlo_a, cnt_a);
  scan_kernel<<<1, 256, 0, stream>>>(cnt_a, jlo_a, off_a, latoff, latcnt,
                                     rowmeta, TAPCAP);
  fill_kernel<<<NROWS, 64, 0, stream>>>(Kgc, Kgs, Kdc, Kds, jlo_a, cnt_a, off_a,
                                        tapw, TAPCAP);

  dim3 gs(6, NLAT * NB);

  // stage 1: k1 from S0; X1 = S0 + dt/2 k1
  stage_kernel<<<gs, 256, 0, stream>>>(h0, uv0, h0, uv0, h0, uv0, h0, uv0, fcor,
                                       latoff, latcnt, rowmeta, tapw,
                                       X1h, X1uv, 0.5f * DTSTEP, 0);
  // stage 2: k2 from X1; X2 = S0 + dt/2 k2
  stage_kernel<<<gs, 256, 0, stream>>>(X1h, X1uv, h0, uv0, h0, uv0, h0, uv0, fcor,
                                       latoff, latcnt, rowmeta, tapw,
                                       X2h, X2uv, 0.5f * DTSTEP, 0);
  // stage 3: k3 from X2; X3 = S0 + dt k3
  stage_kernel<<<gs, 256, 0, stream>>>(X2h, X2uv, h0, uv0, h0, uv0, h0, uv0, fcor,
                                       latoff, latcnt, rowmeta, tapw,
                                       X3h, X3uv, DTSTEP, 0);
  // stage 4: k4 from X3; out = (X1 + 2 X2 + X3 - S0)/3 + dt/6 k4
  stage_kernel<<<gs, 256, 0, stream>>>(X3h, X3uv, h0, uv0, X1h, X1uv, X2h, X2uv, fcor,
                                       latoff, latcnt, rowmeta, tapw,
                                       out_h, out_uv, 0.0f, 1);
}